// Round 3
// baseline (327.775 us; speedup 1.0000x reference)
//
#include <hip/hip_runtime.h>
#include <hip/hip_fp16.h>

#define B_ROWS   16384
#define K_NB     64
#define U_ROWS   100000
#define D_DIM    256
#define TWO_D    512
#define R_BLK    8          // rows per block
#define THREADS  256

// ============ pre-pass: u2e fp32 -> fp16 (row-major [U][256]) ============
// 25.6M elements, 8 per thread: read 32B, write 16B, fully coalesced.
__global__ __launch_bounds__(256)
void cvt_u2e_fp16(const float* __restrict__ src, __half* __restrict__ dst, int n8) {
    const int i = blockIdx.x * 256 + threadIdx.x;
    if (i >= n8) return;
    const float4 a = ((const float4*)src)[2 * i];
    const float4 b = ((const float4*)src)[2 * i + 1];
    const __half2 h0 = __floats2half2_rn(a.x, a.y);
    const __half2 h1 = __floats2half2_rn(a.z, a.w);
    const __half2 h2 = __floats2half2_rn(b.x, b.y);
    const __half2 h3 = __floats2half2_rn(b.z, b.w);
    int4 o;
    o.x = *(const int*)&h0; o.y = *(const int*)&h1;
    o.z = *(const int*)&h2; o.w = *(const int*)&h3;
    ((int4*)dst)[i] = o;
}

// ============ main fused kernel, fp16 neighbor gather ============
// Phase-1 theory (rounds 0-2): gather is capped by the per-CU random-access
// path (~0.13 lines/cy/CU regardless of offered concurrency) — so the only
// lever is fewer lines per row: fp16 rows are 512B = 8 lines, half of fp32.
// Self/v2e/W stay fp32; only the mean-pool operand is rounded.
__global__ __launch_bounds__(THREADS, 4)
void easyrec_fused_h(const int* __restrict__ nodes_u,
                     const int* __restrict__ nodes_v,
                     const int* __restrict__ neighbors,
                     const int* __restrict__ neighbor_counts,
                     const float* __restrict__ u2e,
                     const __half* __restrict__ uh,   // fp16 copy of u2e
                     const float* __restrict__ v2e,
                     const float* __restrict__ W,     // [D, 2D] row-major
                     const float* __restrict__ bias,  // [D]
                     float* __restrict__ out)         // [B]
{
    __shared__ __align__(16) int   nbr_lds[R_BLK * K_NB];
    __shared__ __align__(16) float cat_lds[R_BLK][TWO_D];
    __shared__ float red_lds[R_BLK * 4];
    __shared__ float selfdot_lds[R_BLK];
    __shared__ float bdot_lds[R_BLK];

    const int t    = threadIdx.x;
    const int wave = t >> 6;
    const int lane = t & 63;
    const int row0 = blockIdx.x * R_BLK;

    nbr_lds[t]           = neighbors[(size_t)row0 * K_NB + t];
    nbr_lds[t + THREADS] = neighbors[(size_t)row0 * K_NB + t + THREADS];
    __syncthreads();

    const unsigned colb = (unsigned)lane * 16u;  // fp32 row: lane's float4 (cols 4l..4l+3)
    const unsigned colh = (unsigned)lane * 8u;   // fp16 row: lane's 4 halves (same cols)

    // ---- preamble: self/v/bias dots + self->cat (all fp32 sources) ----
    {
        const float4 b4 = *(const float4*)((const char*)bias + colb);
        #pragma unroll
        for (int rr = 0; rr < 2; ++rr) {
            const int r   = wave + rr * 4;
            const int row = row0 + r;
            const int nu  = __builtin_amdgcn_readfirstlane(nodes_u[row]);
            const int nv  = __builtin_amdgcn_readfirstlane(nodes_v[row]);
            const float4 self4 = *(const float4*)((const char*)u2e + (((size_t)nu) << 10) + colb);
            const float4 v4    = *(const float4*)((const char*)v2e + (((size_t)nv) << 10) + colb);
            *(float4*)(&cat_lds[r][4 * lane]) = self4;
            float sv = self4.x * v4.x + self4.y * v4.y + self4.z * v4.z + self4.w * v4.w;
            float bv = b4.x * v4.x + b4.y * v4.y + b4.z * v4.z + b4.w * v4.w;
            #pragma unroll
            for (int off = 32; off > 0; off >>= 1) {
                sv += __shfl_xor(sv, off, 64);
                bv += __shfl_xor(bv, off, 64);
            }
            if (lane == 0) { selfdot_lds[r] = sv; bdot_lds[r] = bv; }
        }
    }

    // ---- phase 1: dual-row merged fp16 gather ----
    const int rowA = row0 + wave, rowB = rowA + 4;
    const int cntA = __builtin_amdgcn_readfirstlane(neighbor_counts[rowA]);
    const int cntB = __builtin_amdgcn_readfirstlane(neighbor_counts[rowB]);
    const int itA = (cntA + 7) >> 3;
    const int itB = (cntB + 7) >> 3;
    const int itMin = itA < itB ? itA : itB;
    const int itMax = itA > itB ? itA : itB;
    const int baseA = wave * K_NB;
    const int baseB = baseA + 4 * K_NB;

#define LOADH8(P, BASE, KK)                                                         \
    const int4 P##ia = *(const int4*)&nbr_lds[(BASE) + (KK)];                       \
    const int4 P##ib = *(const int4*)&nbr_lds[(BASE) + (KK) + 4];                   \
    const uint2 P##n0 = *(const uint2*)((const char*)uh + (((unsigned)P##ia.x) << 9) + colh); \
    const uint2 P##n1 = *(const uint2*)((const char*)uh + (((unsigned)P##ia.y) << 9) + colh); \
    const uint2 P##n2 = *(const uint2*)((const char*)uh + (((unsigned)P##ia.z) << 9) + colh); \
    const uint2 P##n3 = *(const uint2*)((const char*)uh + (((unsigned)P##ia.w) << 9) + colh); \
    const uint2 P##n4 = *(const uint2*)((const char*)uh + (((unsigned)P##ib.x) << 9) + colh); \
    const uint2 P##n5 = *(const uint2*)((const char*)uh + (((unsigned)P##ib.y) << 9) + colh); \
    const uint2 P##n6 = *(const uint2*)((const char*)uh + (((unsigned)P##ib.z) << 9) + colh); \
    const uint2 P##n7 = *(const uint2*)((const char*)uh + (((unsigned)P##ib.w) << 9) + colh);

#define H2F_LO(u) __half22float2(*(const __half2*)&(u))

#define ACCH1(P, N, ACC, M)                                                         \
    {                                                                               \
        const float2 f_a = H2F_LO(P##N.x);                                          \
        const float2 f_b = H2F_LO(P##N.y);                                          \
        ACC.x += (M) * f_a.x; ACC.y += (M) * f_a.y;                                 \
        ACC.z += (M) * f_b.x; ACC.w += (M) * f_b.y;                                 \
    }

#define ACCH8(P, ACC, CNT, KK)                                                      \
    {                                                                               \
        const float m0 = ((KK) + 0 < (CNT)) ? 1.f : 0.f;                            \
        const float m1 = ((KK) + 1 < (CNT)) ? 1.f : 0.f;                            \
        const float m2 = ((KK) + 2 < (CNT)) ? 1.f : 0.f;                            \
        const float m3 = ((KK) + 3 < (CNT)) ? 1.f : 0.f;                            \
        const float m4 = ((KK) + 4 < (CNT)) ? 1.f : 0.f;                            \
        const float m5 = ((KK) + 5 < (CNT)) ? 1.f : 0.f;                            \
        const float m6 = ((KK) + 6 < (CNT)) ? 1.f : 0.f;                            \
        const float m7 = ((KK) + 7 < (CNT)) ? 1.f : 0.f;                            \
        ACCH1(P, n0, ACC, m0) ACCH1(P, n1, ACC, m1)                                 \
        ACCH1(P, n2, ACC, m2) ACCH1(P, n3, ACC, m3)                                 \
        ACCH1(P, n4, ACC, m4) ACCH1(P, n5, ACC, m5)                                 \
        ACCH1(P, n6, ACC, m6) ACCH1(P, n7, ACC, m7)                                 \
    }

    float4 accA = make_float4(0.f, 0.f, 0.f, 0.f);
    float4 accB = make_float4(0.f, 0.f, 0.f, 0.f);

    for (int i = 0; i < itMin; ++i) {
        const int k = i << 3;
        LOADH8(A, baseA, k)
        LOADH8(B, baseB, k)
        ACCH8(A, accA, cntA, k)
        ACCH8(B, accB, cntB, k)
    }
    if (itMin < itMax) {
        const bool Along = itA > itB;
        const int  cntL  = Along ? cntA : cntB;
        const int  baseL = Along ? baseA : baseB;
        float4 accL = make_float4(0.f, 0.f, 0.f, 0.f);
        for (int i = itMin; i < itMax; ++i) {
            const int k = i << 3;
            LOADH8(L, baseL, k)
            ACCH8(L, accL, cntL, k)
        }
        if (Along) {
            accA.x += accL.x; accA.y += accL.y; accA.z += accL.z; accA.w += accL.w;
        } else {
            accB.x += accL.x; accB.y += accL.y; accB.z += accL.z; accB.w += accL.w;
        }
    }
#undef LOADH8
#undef ACCH8
#undef ACCH1
#undef H2F_LO

    {
        const float invA = 1.0f / (float)(cntA > 0 ? cntA : 1);
        const float invB = 1.0f / (float)(cntB > 0 ? cntB : 1);
        *(float4*)(&cat_lds[wave][D_DIM + 4 * lane]) =
            make_float4(accA.x * invA, accA.y * invA, accA.z * invA, accA.w * invA);
        *(float4*)(&cat_lds[wave + 4][D_DIM + 4 * lane]) =
            make_float4(accB.x * invB, accB.y * invB, accB.z * invB, accB.w * invB);
    }
    __syncthreads();

    // ---- phase 2: t_j = sum_d W[d, j] * v[d]; thread t owns j = 2t, 2t+1 ----
    unsigned voff[R_BLK];
    #pragma unroll
    for (int r = 0; r < R_BLK; ++r) {
        const int nv = __builtin_amdgcn_readfirstlane(nodes_v[row0 + r]);
        voff[r] = ((unsigned)nv) << 10;
    }

    float2 acc2[R_BLK];
    #pragma unroll
    for (int r = 0; r < R_BLK; ++r) acc2[r] = make_float2(0.f, 0.f);

    const unsigned tb8 = (unsigned)t * 8u;
    for (int d = 0; d < D_DIM; d += 4) {
        float4 vq[R_BLK];
        #pragma unroll
        for (int r = 0; r < R_BLK; ++r)
            vq[r] = *(const float4*)((const char*)v2e + voff[r] + (unsigned)d * 4u);

        #pragma unroll
        for (int dd = 0; dd < 4; ++dd) {
            const float2 wq = *(const float2*)((const char*)W + (((unsigned)(d + dd)) << 11) + tb8);
            #pragma unroll
            for (int r = 0; r < R_BLK; ++r) {
                const float vs = (dd == 0) ? vq[r].x : (dd == 1) ? vq[r].y
                               : (dd == 2) ? vq[r].z : vq[r].w;
                acc2[r].x += wq.x * vs;
                acc2[r].y += wq.y * vs;
            }
        }
    }

    #pragma unroll
    for (int r = 0; r < R_BLK; ++r) {
        const float2 c2 = *(const float2*)(&cat_lds[r][2 * t]);
        float p = c2.x * acc2[r].x + c2.y * acc2[r].y;
        #pragma unroll
        for (int off = 32; off > 0; off >>= 1) p += __shfl_xor(p, off, 64);
        if (lane == 0) red_lds[r * 4 + wave] = p;
    }
    __syncthreads();

    if (t < R_BLK) {
        const int row = row0 + t;
        const int cnt = neighbor_counts[row];
        float s;
        if (cnt > 0) {
            s = red_lds[t * 4 + 0] + red_lds[t * 4 + 1]
              + red_lds[t * 4 + 2] + red_lds[t * 4 + 3] + bdot_lds[t];
        } else {
            s = selfdot_lds[t];
        }
        out[row] = s;
    }
}

// ============ fp32 fallback (ws too small): round-0 proven kernel ============
__global__ __launch_bounds__(THREADS, 4)
void easyrec_fused_f(const int* __restrict__ nodes_u,
                     const int* __restrict__ nodes_v,
                     const int* __restrict__ neighbors,
                     const int* __restrict__ neighbor_counts,
                     const float* __restrict__ u2e,
                     const float* __restrict__ v2e,
                     const float* __restrict__ W,
                     const float* __restrict__ bias,
                     float* __restrict__ out)
{
    __shared__ __align__(16) int   nbr_lds[R_BLK * K_NB];
    __shared__ __align__(16) float cat_lds[R_BLK][TWO_D];
    __shared__ float red_lds[R_BLK * 4];
    __shared__ float selfdot_lds[R_BLK];
    __shared__ float bdot_lds[R_BLK];

    const int t    = threadIdx.x;
    const int wave = t >> 6;
    const int lane = t & 63;
    const int row0 = blockIdx.x * R_BLK;

    nbr_lds[t]           = neighbors[(size_t)row0 * K_NB + t];
    nbr_lds[t + THREADS] = neighbors[(size_t)row0 * K_NB + t + THREADS];
    __syncthreads();

    for (int rr = 0; rr < 2; ++rr) {
        const int r   = wave + rr * 4;
        const int row = row0 + r;
        const int nu  = __builtin_amdgcn_readfirstlane(nodes_u[row]);
        const int nv  = __builtin_amdgcn_readfirstlane(nodes_v[row]);
        const int cnt = __builtin_amdgcn_readfirstlane(neighbor_counts[row]);

        const float4 self4 = *(const float4*)(u2e + (size_t)nu * D_DIM + 4 * lane);
        const float4 v4    = *(const float4*)(v2e + (size_t)nv * D_DIM + 4 * lane);
        const float4 b4    = *(const float4*)(bias + 4 * lane);

        float4 acc = make_float4(0.f, 0.f, 0.f, 0.f);
        const int base = r * K_NB;
        const int kmax = (cnt + 7) & ~7;
        for (int k = 0; k < kmax; k += 8) {
            const int4 ia = *(const int4*)&nbr_lds[base + k];
            const int4 ib = *(const int4*)&nbr_lds[base + k + 4];
            const float4 n0 = *(const float4*)(u2e + (size_t)ia.x * D_DIM + 4 * lane);
            const float4 n1 = *(const float4*)(u2e + (size_t)ia.y * D_DIM + 4 * lane);
            const float4 n2 = *(const float4*)(u2e + (size_t)ia.z * D_DIM + 4 * lane);
            const float4 n3 = *(const float4*)(u2e + (size_t)ia.w * D_DIM + 4 * lane);
            const float4 n4 = *(const float4*)(u2e + (size_t)ib.x * D_DIM + 4 * lane);
            const float4 n5 = *(const float4*)(u2e + (size_t)ib.y * D_DIM + 4 * lane);
            const float4 n6 = *(const float4*)(u2e + (size_t)ib.z * D_DIM + 4 * lane);
            const float4 n7 = *(const float4*)(u2e + (size_t)ib.w * D_DIM + 4 * lane);
            const float m0 = (k + 0 < cnt) ? 1.f : 0.f;
            const float m1 = (k + 1 < cnt) ? 1.f : 0.f;
            const float m2 = (k + 2 < cnt) ? 1.f : 0.f;
            const float m3 = (k + 3 < cnt) ? 1.f : 0.f;
            const float m4 = (k + 4 < cnt) ? 1.f : 0.f;
            const float m5 = (k + 5 < cnt) ? 1.f : 0.f;
            const float m6 = (k + 6 < cnt) ? 1.f : 0.f;
            const float m7 = (k + 7 < cnt) ? 1.f : 0.f;
            acc.x += n0.x*m0 + n1.x*m1 + n2.x*m2 + n3.x*m3 + n4.x*m4 + n5.x*m5 + n6.x*m6 + n7.x*m7;
            acc.y += n0.y*m0 + n1.y*m1 + n2.y*m2 + n3.y*m3 + n4.y*m4 + n5.y*m5 + n6.y*m6 + n7.y*m7;
            acc.z += n0.z*m0 + n1.z*m1 + n2.z*m2 + n3.z*m3 + n4.z*m4 + n5.z*m5 + n6.z*m6 + n7.z*m7;
            acc.w += n0.w*m0 + n1.w*m1 + n2.w*m2 + n3.w*m3 + n4.w*m4 + n5.w*m5 + n6.w*m6 + n7.w*m7;
        }
        const float inv = 1.0f / (float)(cnt > 0 ? cnt : 1);
        *(float4*)(&cat_lds[r][4 * lane])         = self4;
        *(float4*)(&cat_lds[r][D_DIM + 4 * lane]) =
            make_float4(acc.x * inv, acc.y * inv, acc.z * inv, acc.w * inv);

        float sv = self4.x * v4.x + self4.y * v4.y + self4.z * v4.z + self4.w * v4.w;
        float bv = b4.x * v4.x + b4.y * v4.y + b4.z * v4.z + b4.w * v4.w;
        #pragma unroll
        for (int off = 32; off > 0; off >>= 1) {
            sv += __shfl_xor(sv, off, 64);
            bv += __shfl_xor(bv, off, 64);
        }
        if (lane == 0) { selfdot_lds[r] = sv; bdot_lds[r] = bv; }
    }
    __syncthreads();

    const float* vrow[R_BLK];
    #pragma unroll
    for (int r = 0; r < R_BLK; ++r) {
        const int nv = __builtin_amdgcn_readfirstlane(nodes_v[row0 + r]);
        vrow[r] = v2e + (size_t)nv * D_DIM;
    }

    float2 acc2[R_BLK];
    #pragma unroll
    for (int r = 0; r < R_BLK; ++r) acc2[r] = make_float2(0.f, 0.f);

    for (int d = 0; d < D_DIM; d += 4) {
        float4 vq[R_BLK];
        #pragma unroll
        for (int r = 0; r < R_BLK; ++r) vq[r] = *(const float4*)(vrow[r] + d);
        #pragma unroll
        for (int dd = 0; dd < 4; ++dd) {
            const float2 wq = *(const float2*)(W + (size_t)(d + dd) * TWO_D + 2 * t);
            #pragma unroll
            for (int r = 0; r < R_BLK; ++r) {
                const float vs = (dd == 0) ? vq[r].x : (dd == 1) ? vq[r].y
                               : (dd == 2) ? vq[r].z : vq[r].w;
                acc2[r].x += wq.x * vs;
                acc2[r].y += wq.y * vs;
            }
        }
    }

    #pragma unroll
    for (int r = 0; r < R_BLK; ++r) {
        const float2 c2 = *(const float2*)(&cat_lds[r][2 * t]);
        float p = c2.x * acc2[r].x + c2.y * acc2[r].y;
        #pragma unroll
        for (int off = 32; off > 0; off >>= 1) p += __shfl_xor(p, off, 64);
        if (lane == 0) red_lds[r * 4 + wave] = p;
    }
    __syncthreads();

    if (t < R_BLK) {
        const int row = row0 + t;
        const int cnt = neighbor_counts[row];
        float s;
        if (cnt > 0) {
            s = red_lds[t * 4 + 0] + red_lds[t * 4 + 1]
              + red_lds[t * 4 + 2] + red_lds[t * 4 + 3] + bdot_lds[t];
        } else {
            s = selfdot_lds[t];
        }
        out[row] = s;
    }
}

extern "C" void kernel_launch(void* const* d_in, const int* in_sizes, int n_in,
                              void* d_out, int out_size, void* d_ws, size_t ws_size,
                              hipStream_t stream) {
    const int*   nodes_u         = (const int*)d_in[0];
    const int*   nodes_v         = (const int*)d_in[1];
    const int*   neighbors       = (const int*)d_in[2];
    const int*   neighbor_counts = (const int*)d_in[3];
    const float* u2e             = (const float*)d_in[4];
    const float* v2e             = (const float*)d_in[5];
    const float* W               = (const float*)d_in[6];
    const float* bias            = (const float*)d_in[7];
    float*       out             = (float*)d_out;

    const size_t need = (size_t)U_ROWS * D_DIM * sizeof(__half);  // 51.2 MB
    const int blocks = B_ROWS / R_BLK;   // 2048

    if (d_ws != nullptr && ws_size >= need) {
        __half* uh = (__half*)d_ws;
        const int n8 = U_ROWS * D_DIM / 8;               // 3.2M
        const int cblocks = (n8 + 255) / 256;            // 12500
        cvt_u2e_fp16<<<cblocks, 256, 0, stream>>>(u2e, uh, n8);
        easyrec_fused_h<<<blocks, THREADS, 0, stream>>>(
            nodes_u, nodes_v, neighbors, neighbor_counts, u2e, uh, v2e, W, bias, out);
    } else {
        easyrec_fused_f<<<blocks, THREADS, 0, stream>>>(
            nodes_u, nodes_v, neighbors, neighbor_counts, u2e, v2e, W, bias, out);
    }
}

// Round 4
// 327.259 us; speedup vs baseline: 1.0016x; 1.0016x over previous
//
#include <hip/hip_runtime.h>
#include <hip/hip_fp16.h>

#define B_ROWS   16384
#define K_NB     64
#define U_ROWS   100000
#define D_DIM    256
#define TWO_D    512
#define R_BLK    8          // rows per block
#define THREADS  256

// ============ pre-pass: u2e fp32 -> fp16 (row-major [U][256]) ============
// 150 MB streamed at ~5.2 TB/s ~= 29 us — at the BW floor, not worth touching.
__global__ __launch_bounds__(256)
void cvt_u2e_fp16(const float* __restrict__ src, __half* __restrict__ dst, int n8) {
    const int i = blockIdx.x * 256 + threadIdx.x;
    if (i >= n8) return;
    const float4 a = ((const float4*)src)[2 * i];
    const float4 b = ((const float4*)src)[2 * i + 1];
    const __half2 h0 = __floats2half2_rn(a.x, a.y);
    const __half2 h1 = __floats2half2_rn(a.z, a.w);
    const __half2 h2 = __floats2half2_rn(b.x, b.y);
    const __half2 h3 = __floats2half2_rn(b.z, b.w);
    int4 o;
    o.x = *(const int*)&h0; o.y = *(const int*)&h1;
    o.z = *(const int*)&h2; o.w = *(const int*)&h3;
    ((int4*)dst)[i] = o;
}

__device__ __forceinline__ float2 h2f(unsigned u) {
    const __half2 h = *(const __half2*)&u;
    return __half22float2(h);
}

// ============ main fused kernel ============
// Round-3 evidence: after fp16 (lines/row halved, instr/row unchanged) phase 1
// is vmem-INSTRUCTION/latency capped, not line capped. This version halves wave
// load-instructions per gathered row again: lane loads uint4 (16B = 8 fp16 cols),
// 32 lanes cover a row, so ONE instruction gathers a neighbor of row A (lanes
// 0-31) AND a neighbor of row B (lanes 32-63). Line count stays compulsory.
__global__ __launch_bounds__(THREADS, 4)
void easyrec_fused_h(const int* __restrict__ nodes_u,
                     const int* __restrict__ nodes_v,
                     const int* __restrict__ neighbors,
                     const int* __restrict__ neighbor_counts,
                     const float* __restrict__ u2e,
                     const __half* __restrict__ uh,   // fp16 copy of u2e
                     const float* __restrict__ v2e,
                     const float* __restrict__ W,     // [D, 2D] row-major
                     const float* __restrict__ bias,  // [D]
                     float* __restrict__ out)         // [B]
{
    __shared__ __align__(16) int   nbr_lds[R_BLK * K_NB];
    __shared__ __align__(16) float cat_lds[R_BLK][TWO_D];
    __shared__ float red_lds[R_BLK * 4];
    __shared__ float selfdot_lds[R_BLK];
    __shared__ float bdot_lds[R_BLK];

    const int t    = threadIdx.x;
    const int wave = t >> 6;
    const int lane = t & 63;
    const int hi   = lane >> 5;      // 0: serves row A, 1: serves row B
    const int lsub = lane & 31;
    const int row0 = blockIdx.x * R_BLK;

    nbr_lds[t]           = neighbors[(size_t)row0 * K_NB + t];
    nbr_lds[t + THREADS] = neighbors[(size_t)row0 * K_NB + t + THREADS];
    __syncthreads();

    const unsigned colb = (unsigned)lane * 16u;   // fp32 row: lane's float4
    const unsigned colh = (unsigned)lsub * 16u;   // fp16 row: lane's uint4 (8 cols)

    // ---- preamble: self/v/bias dots + self->cat (all fp32 sources) ----
    {
        const float4 b4 = *(const float4*)((const char*)bias + colb);
        #pragma unroll
        for (int rr = 0; rr < 2; ++rr) {
            const int r   = wave + rr * 4;
            const int row = row0 + r;
            const int nu  = __builtin_amdgcn_readfirstlane(nodes_u[row]);
            const int nv  = __builtin_amdgcn_readfirstlane(nodes_v[row]);
            const float4 self4 = *(const float4*)((const char*)u2e + (((size_t)nu) << 10) + colb);
            const float4 v4    = *(const float4*)((const char*)v2e + (((size_t)nv) << 10) + colb);
            *(float4*)(&cat_lds[r][4 * lane]) = self4;
            float sv = self4.x * v4.x + self4.y * v4.y + self4.z * v4.z + self4.w * v4.w;
            float bv = b4.x * v4.x + b4.y * v4.y + b4.z * v4.z + b4.w * v4.w;
            #pragma unroll
            for (int off = 32; off > 0; off >>= 1) {
                sv += __shfl_xor(sv, off, 64);
                bv += __shfl_xor(bv, off, 64);
            }
            if (lane == 0) { selfdot_lds[r] = sv; bdot_lds[r] = bv; }
        }
    }

    // ---- phase 1: half-wave-per-row fp16 gather ----
    const int rowA = row0 + wave, rowB = rowA + 4;
    const int cntA = __builtin_amdgcn_readfirstlane(neighbor_counts[rowA]);
    const int cntB = __builtin_amdgcn_readfirstlane(neighbor_counts[rowB]);
    const int itA  = (cntA + 7) >> 3;
    const int itB  = (cntB + 7) >> 3;
    const int itMin = itA < itB ? itA : itB;
    const int baseA = wave * K_NB;
    const int baseB = baseA + 4 * K_NB;

    const int cntS  = hi ? cntB : cntA;    // this half-wave's row count
    const int baseS = hi ? baseB : baseA;  // this half-wave's index base

    float acc[8];
    #pragma unroll
    for (int d = 0; d < 8; ++d) acc[d] = 0.f;

#define ACCU4(V, M, ACC)                                                     \
    {                                                                        \
        uint4 vz = (V);                                                      \
        if (!(M)) { vz.x = 0u; vz.y = 0u; vz.z = 0u; vz.w = 0u; }            \
        const float2 f0 = h2f(vz.x), f1 = h2f(vz.y);                         \
        const float2 f2 = h2f(vz.z), f3 = h2f(vz.w);                         \
        ACC[0] += f0.x; ACC[1] += f0.y; ACC[2] += f1.x; ACC[3] += f1.y;      \
        ACC[4] += f2.x; ACC[5] += f2.y; ACC[6] += f3.x; ACC[7] += f3.y;      \
    }

    // common part: lanes 0-31 gather row A's neighbors k..k+7, lanes 32-63 row B's.
    // 8 uint4 loads in flight covering 16 neighbor-rows (was 16 loads).
    for (int i = 0; i < itMin; ++i) {
        const int k = i << 3;
        const int4 ia = *(const int4*)&nbr_lds[baseS + k];       // per-half broadcast
        const int4 ib = *(const int4*)&nbr_lds[baseS + k + 4];
        const uint4 n0 = *(const uint4*)((const char*)uh + (((unsigned)ia.x) << 9) + colh);
        const uint4 n1 = *(const uint4*)((const char*)uh + (((unsigned)ia.y) << 9) + colh);
        const uint4 n2 = *(const uint4*)((const char*)uh + (((unsigned)ia.z) << 9) + colh);
        const uint4 n3 = *(const uint4*)((const char*)uh + (((unsigned)ia.w) << 9) + colh);
        const uint4 n4 = *(const uint4*)((const char*)uh + (((unsigned)ib.x) << 9) + colh);
        const uint4 n5 = *(const uint4*)((const char*)uh + (((unsigned)ib.y) << 9) + colh);
        const uint4 n6 = *(const uint4*)((const char*)uh + (((unsigned)ib.z) << 9) + colh);
        const uint4 n7 = *(const uint4*)((const char*)uh + (((unsigned)ib.w) << 9) + colh);
        ACCU4(n0, k + 0 < cntS, acc)
        ACCU4(n1, k + 1 < cntS, acc)
        ACCU4(n2, k + 2 < cntS, acc)
        ACCU4(n3, k + 3 < cntS, acc)
        ACCU4(n4, k + 4 < cntS, acc)
        ACCU4(n5, k + 5 < cntS, acc)
        ACCU4(n6, k + 6 < cntS, acc)
        ACCU4(n7, k + 7 < cntS, acc)
    }

    // tail: only the longer row remains; both half-waves work it (lo: k..k+3,
    // hi: k+4..k+7), combined afterwards with one xor-32 butterfly.
    const int itMax = itA > itB ? itA : itB;
    if (itMin < itMax) {
        const bool Along = itA > itB;
        const int  cntL  = Along ? cntA : cntB;
        const int  baseL = Along ? baseA : baseB;
        float accT[8];
        #pragma unroll
        for (int d = 0; d < 8; ++d) accT[d] = 0.f;

        for (int i = itMin; i < itMax; ++i) {
            const int k  = i << 3;
            const int kb = k + 4 * hi;
            const int4 it4 = *(const int4*)&nbr_lds[baseL + kb];
            const uint4 n0 = *(const uint4*)((const char*)uh + (((unsigned)it4.x) << 9) + colh);
            const uint4 n1 = *(const uint4*)((const char*)uh + (((unsigned)it4.y) << 9) + colh);
            const uint4 n2 = *(const uint4*)((const char*)uh + (((unsigned)it4.z) << 9) + colh);
            const uint4 n3 = *(const uint4*)((const char*)uh + (((unsigned)it4.w) << 9) + colh);
            ACCU4(n0, kb + 0 < cntL, accT)
            ACCU4(n1, kb + 1 < cntL, accT)
            ACCU4(n2, kb + 2 < cntL, accT)
            ACCU4(n3, kb + 3 < cntL, accT)
        }
        #pragma unroll
        for (int d = 0; d < 8; ++d) accT[d] += __shfl_xor(accT[d], 32, 64);
        const float addm = ((hi == 0) == Along) ? 1.f : 0.f;
        #pragma unroll
        for (int d = 0; d < 8; ++d) acc[d] += addm * accT[d];
    }
#undef ACCU4

    {
        const float invS = 1.0f / (float)(cntS > 0 ? cntS : 1);
        const int   rloc = wave + 4 * hi;
        *(float4*)(&cat_lds[rloc][D_DIM + 8 * lsub]) =
            make_float4(acc[0] * invS, acc[1] * invS, acc[2] * invS, acc[3] * invS);
        *(float4*)(&cat_lds[rloc][D_DIM + 8 * lsub + 4]) =
            make_float4(acc[4] * invS, acc[5] * invS, acc[6] * invS, acc[7] * invS);
    }
    __syncthreads();

    // ---- phase 2: t_j = sum_d W[d, j] * v[d]; thread t owns j = 2t, 2t+1 ----
    unsigned voff[R_BLK];
    #pragma unroll
    for (int r = 0; r < R_BLK; ++r) {
        const int nv = __builtin_amdgcn_readfirstlane(nodes_v[row0 + r]);
        voff[r] = ((unsigned)nv) << 10;
    }

    float2 acc2[R_BLK];
    #pragma unroll
    for (int r = 0; r < R_BLK; ++r) acc2[r] = make_float2(0.f, 0.f);

    const unsigned tb8 = (unsigned)t * 8u;
    for (int d = 0; d < D_DIM; d += 4) {
        float4 vq[R_BLK];
        #pragma unroll
        for (int r = 0; r < R_BLK; ++r)
            vq[r] = *(const float4*)((const char*)v2e + voff[r] + (unsigned)d * 4u);

        #pragma unroll
        for (int dd = 0; dd < 4; ++dd) {
            const float2 wq = *(const float2*)((const char*)W + (((unsigned)(d + dd)) << 11) + tb8);
            #pragma unroll
            for (int r = 0; r < R_BLK; ++r) {
                const float vs = (dd == 0) ? vq[r].x : (dd == 1) ? vq[r].y
                               : (dd == 2) ? vq[r].z : vq[r].w;
                acc2[r].x += wq.x * vs;
                acc2[r].y += wq.y * vs;
            }
        }
    }

    #pragma unroll
    for (int r = 0; r < R_BLK; ++r) {
        const float2 c2 = *(const float2*)(&cat_lds[r][2 * t]);
        float p = c2.x * acc2[r].x + c2.y * acc2[r].y;
        #pragma unroll
        for (int off = 32; off > 0; off >>= 1) p += __shfl_xor(p, off, 64);
        if (lane == 0) red_lds[r * 4 + wave] = p;
    }
    __syncthreads();

    if (t < R_BLK) {
        const int row = row0 + t;
        const int cnt = neighbor_counts[row];
        float s;
        if (cnt > 0) {
            s = red_lds[t * 4 + 0] + red_lds[t * 4 + 1]
              + red_lds[t * 4 + 2] + red_lds[t * 4 + 3] + bdot_lds[t];
        } else {
            s = selfdot_lds[t];
        }
        out[row] = s;
    }
}

// ============ fp32 fallback (ws too small): round-0 proven kernel ============
__global__ __launch_bounds__(THREADS, 4)
void easyrec_fused_f(const int* __restrict__ nodes_u,
                     const int* __restrict__ nodes_v,
                     const int* __restrict__ neighbors,
                     const int* __restrict__ neighbor_counts,
                     const float* __restrict__ u2e,
                     const float* __restrict__ v2e,
                     const float* __restrict__ W,
                     const float* __restrict__ bias,
                     float* __restrict__ out)
{
    __shared__ __align__(16) int   nbr_lds[R_BLK * K_NB];
    __shared__ __align__(16) float cat_lds[R_BLK][TWO_D];
    __shared__ float red_lds[R_BLK * 4];
    __shared__ float selfdot_lds[R_BLK];
    __shared__ float bdot_lds[R_BLK];

    const int t    = threadIdx.x;
    const int wave = t >> 6;
    const int lane = t & 63;
    const int row0 = blockIdx.x * R_BLK;

    nbr_lds[t]           = neighbors[(size_t)row0 * K_NB + t];
    nbr_lds[t + THREADS] = neighbors[(size_t)row0 * K_NB + t + THREADS];
    __syncthreads();

    for (int rr = 0; rr < 2; ++rr) {
        const int r   = wave + rr * 4;
        const int row = row0 + r;
        const int nu  = __builtin_amdgcn_readfirstlane(nodes_u[row]);
        const int nv  = __builtin_amdgcn_readfirstlane(nodes_v[row]);
        const int cnt = __builtin_amdgcn_readfirstlane(neighbor_counts[row]);

        const float4 self4 = *(const float4*)(u2e + (size_t)nu * D_DIM + 4 * lane);
        const float4 v4    = *(const float4*)(v2e + (size_t)nv * D_DIM + 4 * lane);
        const float4 b4    = *(const float4*)(bias + 4 * lane);

        float4 acc = make_float4(0.f, 0.f, 0.f, 0.f);
        const int base = r * K_NB;
        const int kmax = (cnt + 7) & ~7;
        for (int k = 0; k < kmax; k += 8) {
            const int4 ia = *(const int4*)&nbr_lds[base + k];
            const int4 ib = *(const int4*)&nbr_lds[base + k + 4];
            const float4 n0 = *(const float4*)(u2e + (size_t)ia.x * D_DIM + 4 * lane);
            const float4 n1 = *(const float4*)(u2e + (size_t)ia.y * D_DIM + 4 * lane);
            const float4 n2 = *(const float4*)(u2e + (size_t)ia.z * D_DIM + 4 * lane);
            const float4 n3 = *(const float4*)(u2e + (size_t)ia.w * D_DIM + 4 * lane);
            const float4 n4 = *(const float4*)(u2e + (size_t)ib.x * D_DIM + 4 * lane);
            const float4 n5 = *(const float4*)(u2e + (size_t)ib.y * D_DIM + 4 * lane);
            const float4 n6 = *(const float4*)(u2e + (size_t)ib.z * D_DIM + 4 * lane);
            const float4 n7 = *(const float4*)(u2e + (size_t)ib.w * D_DIM + 4 * lane);
            const float m0 = (k + 0 < cnt) ? 1.f : 0.f;
            const float m1 = (k + 1 < cnt) ? 1.f : 0.f;
            const float m2 = (k + 2 < cnt) ? 1.f : 0.f;
            const float m3 = (k + 3 < cnt) ? 1.f : 0.f;
            const float m4 = (k + 4 < cnt) ? 1.f : 0.f;
            const float m5 = (k + 5 < cnt) ? 1.f : 0.f;
            const float m6 = (k + 6 < cnt) ? 1.f : 0.f;
            const float m7 = (k + 7 < cnt) ? 1.f : 0.f;
            acc.x += n0.x*m0 + n1.x*m1 + n2.x*m2 + n3.x*m3 + n4.x*m4 + n5.x*m5 + n6.x*m6 + n7.x*m7;
            acc.y += n0.y*m0 + n1.y*m1 + n2.y*m2 + n3.y*m3 + n4.y*m4 + n5.y*m5 + n6.y*m6 + n7.y*m7;
            acc.z += n0.z*m0 + n1.z*m1 + n2.z*m2 + n3.z*m3 + n4.z*m4 + n5.z*m5 + n6.z*m6 + n7.z*m7;
            acc.w += n0.w*m0 + n1.w*m1 + n2.w*m2 + n3.w*m3 + n4.w*m4 + n5.w*m5 + n6.w*m6 + n7.w*m7;
        }
        const float inv = 1.0f / (float)(cnt > 0 ? cnt : 1);
        *(float4*)(&cat_lds[r][4 * lane])         = self4;
        *(float4*)(&cat_lds[r][D_DIM + 4 * lane]) =
            make_float4(acc.x * inv, acc.y * inv, acc.z * inv, acc.w * inv);

        float sv = self4.x * v4.x + self4.y * v4.y + self4.z * v4.z + self4.w * v4.w;
        float bv = b4.x * v4.x + b4.y * v4.y + b4.z * v4.z + b4.w * v4.w;
        #pragma unroll
        for (int off = 32; off > 0; off >>= 1) {
            sv += __shfl_xor(sv, off, 64);
            bv += __shfl_xor(bv, off, 64);
        }
        if (lane == 0) { selfdot_lds[r] = sv; bdot_lds[r] = bv; }
    }
    __syncthreads();

    const float* vrow[R_BLK];
    #pragma unroll
    for (int r = 0; r < R_BLK; ++r) {
        const int nv = __builtin_amdgcn_readfirstlane(nodes_v[row0 + r]);
        vrow[r] = v2e + (size_t)nv * D_DIM;
    }

    float2 acc2[R_BLK];
    #pragma unroll
    for (int r = 0; r < R_BLK; ++r) acc2[r] = make_float2(0.f, 0.f);

    for (int d = 0; d < D_DIM; d += 4) {
        float4 vq[R_BLK];
        #pragma unroll
        for (int r = 0; r < R_BLK; ++r) vq[r] = *(const float4*)(vrow[r] + d);
        #pragma unroll
        for (int dd = 0; dd < 4; ++dd) {
            const float2 wq = *(const float2*)(W + (size_t)(d + dd) * TWO_D + 2 * t);
            #pragma unroll
            for (int r = 0; r < R_BLK; ++r) {
                const float vs = (dd == 0) ? vq[r].x : (dd == 1) ? vq[r].y
                               : (dd == 2) ? vq[r].z : vq[r].w;
                acc2[r].x += wq.x * vs;
                acc2[r].y += wq.y * vs;
            }
        }
    }

    #pragma unroll
    for (int r = 0; r < R_BLK; ++r) {
        const float2 c2 = *(const float2*)(&cat_lds[r][2 * t]);
        float p = c2.x * acc2[r].x + c2.y * acc2[r].y;
        #pragma unroll
        for (int off = 32; off > 0; off >>= 1) p += __shfl_xor(p, off, 64);
        if (lane == 0) red_lds[r * 4 + wave] = p;
    }
    __syncthreads();

    if (t < R_BLK) {
        const int row = row0 + t;
        const int cnt = neighbor_counts[row];
        float s;
        if (cnt > 0) {
            s = red_lds[t * 4 + 0] + red_lds[t * 4 + 1]
              + red_lds[t * 4 + 2] + red_lds[t * 4 + 3] + bdot_lds[t];
        } else {
            s = selfdot_lds[t];
        }
        out[row] = s;
    }
}

extern "C" void kernel_launch(void* const* d_in, const int* in_sizes, int n_in,
                              void* d_out, int out_size, void* d_ws, size_t ws_size,
                              hipStream_t stream) {
    const int*   nodes_u         = (const int*)d_in[0];
    const int*   nodes_v         = (const int*)d_in[1];
    const int*   neighbors       = (const int*)d_in[2];
    const int*   neighbor_counts = (const int*)d_in[3];
    const float* u2e             = (const float*)d_in[4];
    const float* v2e             = (const float*)d_in[5];
    const float* W               = (const float*)d_in[6];
    const float* bias            = (const float*)d_in[7];
    float*       out             = (float*)d_out;

    const size_t need = (size_t)U_ROWS * D_DIM * sizeof(__half);  // 51.2 MB
    const int blocks = B_ROWS / R_BLK;   // 2048

    if (d_ws != nullptr && ws_size >= need) {
        __half* uh = (__half*)d_ws;
        const int n8 = U_ROWS * D_DIM / 8;               // 3.2M
        const int cblocks = (n8 + 255) / 256;            // 12500
        cvt_u2e_fp16<<<cblocks, 256, 0, stream>>>(u2e, uh, n8);
        easyrec_fused_h<<<blocks, THREADS, 0, stream>>>(
            nodes_u, nodes_v, neighbors, neighbor_counts, u2e, uh, v2e, W, bias, out);
    } else {
        easyrec_fused_f<<<blocks, THREADS, 0, stream>>>(
            nodes_u, nodes_v, neighbors, neighbor_counts, u2e, v2e, W, bias, out);
    }
}

// Round 5
// 302.591 us; speedup vs baseline: 1.0832x; 1.0815x over previous
//
#include <hip/hip_runtime.h>
#include <hip/hip_fp16.h>

#define B_ROWS   16384
#define K_NB     64
#define U_ROWS   100000
#define D_DIM    256
#define TWO_D    512
#define R_BLK    8          // rows per block
#define THREADS  256

typedef float f32x2_t __attribute__((ext_vector_type(2)));

#if __has_builtin(__builtin_amdgcn_cvt_pk_f32_fp8) && __has_builtin(__builtin_amdgcn_cvt_pk_fp8_f32)
#define FP8_HW 1
#else
#define FP8_HW 0
#include <hip/hip_fp8.h>
#endif

__device__ __forceinline__ unsigned pack4_fp8(float a, float b, float c, float d) {
#if FP8_HW
    int v = 0;
    v = __builtin_amdgcn_cvt_pk_fp8_f32(a, b, v, false);   // bytes 0-1
    v = __builtin_amdgcn_cvt_pk_fp8_f32(c, d, v, true);    // bytes 2-3
    return (unsigned)v;
#else
    __hip_fp8_e4m3 x0(a), x1(b), x2(c), x3(d);
    return (unsigned)x0.__x | ((unsigned)x1.__x << 8)
         | ((unsigned)x2.__x << 16) | ((unsigned)x3.__x << 24);
#endif
}

__device__ __forceinline__ float4 unpack4_fp8(unsigned u) {
#if FP8_HW
    const f32x2_t lo = __builtin_amdgcn_cvt_pk_f32_fp8((int)u, false);
    const f32x2_t hi = __builtin_amdgcn_cvt_pk_f32_fp8((int)u, true);
    return make_float4(lo[0], lo[1], hi[0], hi[1]);
#else
    __hip_fp8_e4m3 x0, x1, x2, x3;
    x0.__x = u & 0xff; x1.__x = (u >> 8) & 0xff;
    x2.__x = (u >> 16) & 0xff; x3.__x = (u >> 24) & 0xff;
    return make_float4((float)x0, (float)x1, (float)x2, (float)x3);
#endif
}

// ============ pre-pass: u2e fp32 -> fp8 e4m3 (row-major [U][256]) ============
// reads 100 MB + writes 25.6 MB, BW-bound ~24 us.
__global__ __launch_bounds__(256)
void cvt_u2e_fp8(const float* __restrict__ src, uint2* __restrict__ dst, int n8) {
    const int i = blockIdx.x * 256 + threadIdx.x;
    if (i >= n8) return;
    const float4 a = ((const float4*)src)[2 * i];
    const float4 b = ((const float4*)src)[2 * i + 1];
    uint2 o;
    o.x = pack4_fp8(a.x, a.y, a.z, a.w);
    o.y = pack4_fp8(b.x, b.y, b.z, b.w);
    dst[i] = o;
}

// ============ main fused kernel, fp8 neighbor gather ============
// Evidence r0-r4: gather is capped ONLY by bytes/lines fetched (ILP null,
// instruction count null, bytes 2x -> 1.28x). fp8 rows are 256B = 4 lines,
// half of fp16. One dword load per neighbor-row (lane owns cols 4l..4l+3),
// HW packed fp8->f32 converters keep unpack at 2 cvt_pk + 4 fma per row.
__global__ __launch_bounds__(THREADS, 4)
void easyrec_fused_q(const int* __restrict__ nodes_u,
                     const int* __restrict__ nodes_v,
                     const int* __restrict__ neighbors,
                     const int* __restrict__ neighbor_counts,
                     const float* __restrict__ u2e,
                     const unsigned char* __restrict__ u8,  // fp8 copy of u2e
                     const float* __restrict__ v2e,
                     const float* __restrict__ W,     // [D, 2D] row-major
                     const float* __restrict__ bias,  // [D]
                     float* __restrict__ out)         // [B]
{
    __shared__ __align__(16) int   nbr_lds[R_BLK * K_NB];
    __shared__ __align__(16) float cat_lds[R_BLK][TWO_D];
    __shared__ float red_lds[R_BLK * 4];
    __shared__ float selfdot_lds[R_BLK];
    __shared__ float bdot_lds[R_BLK];

    const int t    = threadIdx.x;
    const int wave = t >> 6;
    const int lane = t & 63;
    const int row0 = blockIdx.x * R_BLK;

    nbr_lds[t]           = neighbors[(size_t)row0 * K_NB + t];
    nbr_lds[t + THREADS] = neighbors[(size_t)row0 * K_NB + t + THREADS];
    __syncthreads();

    const unsigned colb = (unsigned)lane * 16u;   // fp32 row: lane's float4
    const unsigned colq = (unsigned)lane * 4u;    // fp8 row: lane's 4 bytes (same cols)

    // ---- preamble: self/v/bias dots + self->cat (all fp32 sources) ----
    {
        const float4 b4 = *(const float4*)((const char*)bias + colb);
        #pragma unroll
        for (int rr = 0; rr < 2; ++rr) {
            const int r   = wave + rr * 4;
            const int row = row0 + r;
            const int nu  = __builtin_amdgcn_readfirstlane(nodes_u[row]);
            const int nv  = __builtin_amdgcn_readfirstlane(nodes_v[row]);
            const float4 self4 = *(const float4*)((const char*)u2e + (((size_t)nu) << 10) + colb);
            const float4 v4    = *(const float4*)((const char*)v2e + (((size_t)nv) << 10) + colb);
            *(float4*)(&cat_lds[r][4 * lane]) = self4;
            float sv = self4.x * v4.x + self4.y * v4.y + self4.z * v4.z + self4.w * v4.w;
            float bv = b4.x * v4.x + b4.y * v4.y + b4.z * v4.z + b4.w * v4.w;
            #pragma unroll
            for (int off = 32; off > 0; off >>= 1) {
                sv += __shfl_xor(sv, off, 64);
                bv += __shfl_xor(bv, off, 64);
            }
            if (lane == 0) { selfdot_lds[r] = sv; bdot_lds[r] = bv; }
        }
    }

    // ---- phase 1: dual-row merged fp8 gather (R3 structure, dtype-swapped) ----
    const int rowA = row0 + wave, rowB = rowA + 4;
    const int cntA = __builtin_amdgcn_readfirstlane(neighbor_counts[rowA]);
    const int cntB = __builtin_amdgcn_readfirstlane(neighbor_counts[rowB]);
    const int itA = (cntA + 7) >> 3;
    const int itB = (cntB + 7) >> 3;
    const int itMin = itA < itB ? itA : itB;
    const int itMax = itA > itB ? itA : itB;
    const int baseA = wave * K_NB;
    const int baseB = baseA + 4 * K_NB;

#define LOADQ8(P, BASE, KK)                                                         \
    const int4 P##ia = *(const int4*)&nbr_lds[(BASE) + (KK)];                       \
    const int4 P##ib = *(const int4*)&nbr_lds[(BASE) + (KK) + 4];                   \
    const unsigned P##n0 = *(const unsigned*)(u8 + (((unsigned)P##ia.x) << 8) + colq); \
    const unsigned P##n1 = *(const unsigned*)(u8 + (((unsigned)P##ia.y) << 8) + colq); \
    const unsigned P##n2 = *(const unsigned*)(u8 + (((unsigned)P##ia.z) << 8) + colq); \
    const unsigned P##n3 = *(const unsigned*)(u8 + (((unsigned)P##ia.w) << 8) + colq); \
    const unsigned P##n4 = *(const unsigned*)(u8 + (((unsigned)P##ib.x) << 8) + colq); \
    const unsigned P##n5 = *(const unsigned*)(u8 + (((unsigned)P##ib.y) << 8) + colq); \
    const unsigned P##n6 = *(const unsigned*)(u8 + (((unsigned)P##ib.z) << 8) + colq); \
    const unsigned P##n7 = *(const unsigned*)(u8 + (((unsigned)P##ib.w) << 8) + colq);

#define ACCQ1(P, N, ACC, M)                                                         \
    {                                                                               \
        const float4 f = unpack4_fp8(P##N);                                         \
        ACC.x += (M) * f.x; ACC.y += (M) * f.y;                                     \
        ACC.z += (M) * f.z; ACC.w += (M) * f.w;                                     \
    }

#define ACCQ8(P, ACC, CNT, KK)                                                      \
    {                                                                               \
        const float m0 = ((KK) + 0 < (CNT)) ? 1.f : 0.f;                            \
        const float m1 = ((KK) + 1 < (CNT)) ? 1.f : 0.f;                            \
        const float m2 = ((KK) + 2 < (CNT)) ? 1.f : 0.f;                            \
        const float m3 = ((KK) + 3 < (CNT)) ? 1.f : 0.f;                            \
        const float m4 = ((KK) + 4 < (CNT)) ? 1.f : 0.f;                            \
        const float m5 = ((KK) + 5 < (CNT)) ? 1.f : 0.f;                            \
        const float m6 = ((KK) + 6 < (CNT)) ? 1.f : 0.f;                            \
        const float m7 = ((KK) + 7 < (CNT)) ? 1.f : 0.f;                            \
        ACCQ1(P, n0, ACC, m0) ACCQ1(P, n1, ACC, m1)                                 \
        ACCQ1(P, n2, ACC, m2) ACCQ1(P, n3, ACC, m3)                                 \
        ACCQ1(P, n4, ACC, m4) ACCQ1(P, n5, ACC, m5)                                 \
        ACCQ1(P, n6, ACC, m6) ACCQ1(P, n7, ACC, m7)                                 \
    }

    float4 accA = make_float4(0.f, 0.f, 0.f, 0.f);
    float4 accB = make_float4(0.f, 0.f, 0.f, 0.f);

    for (int i = 0; i < itMin; ++i) {
        const int k = i << 3;
        LOADQ8(A, baseA, k)
        LOADQ8(B, baseB, k)
        ACCQ8(A, accA, cntA, k)
        ACCQ8(B, accB, cntB, k)
    }
    if (itMin < itMax) {
        const bool Along = itA > itB;
        const int  cntL  = Along ? cntA : cntB;
        const int  baseL = Along ? baseA : baseB;
        float4 accL = make_float4(0.f, 0.f, 0.f, 0.f);
        for (int i = itMin; i < itMax; ++i) {
            const int k = i << 3;
            LOADQ8(L, baseL, k)
            ACCQ8(L, accL, cntL, k)
        }
        if (Along) {
            accA.x += accL.x; accA.y += accL.y; accA.z += accL.z; accA.w += accL.w;
        } else {
            accB.x += accL.x; accB.y += accL.y; accB.z += accL.z; accB.w += accL.w;
        }
    }
#undef LOADQ8
#undef ACCQ8
#undef ACCQ1

    {
        const float invA = 1.0f / (float)(cntA > 0 ? cntA : 1);
        const float invB = 1.0f / (float)(cntB > 0 ? cntB : 1);
        *(float4*)(&cat_lds[wave][D_DIM + 4 * lane]) =
            make_float4(accA.x * invA, accA.y * invA, accA.z * invA, accA.w * invA);
        *(float4*)(&cat_lds[wave + 4][D_DIM + 4 * lane]) =
            make_float4(accB.x * invB, accB.y * invB, accB.z * invB, accB.w * invB);
    }
    __syncthreads();

    // ---- phase 2: t_j = sum_d W[d, j] * v[d]; thread t owns j = 2t, 2t+1 ----
    unsigned voff[R_BLK];
    #pragma unroll
    for (int r = 0; r < R_BLK; ++r) {
        const int nv = __builtin_amdgcn_readfirstlane(nodes_v[row0 + r]);
        voff[r] = ((unsigned)nv) << 10;
    }

    float2 acc2[R_BLK];
    #pragma unroll
    for (int r = 0; r < R_BLK; ++r) acc2[r] = make_float2(0.f, 0.f);

    const unsigned tb8 = (unsigned)t * 8u;
    for (int d = 0; d < D_DIM; d += 4) {
        float4 vq[R_BLK];
        #pragma unroll
        for (int r = 0; r < R_BLK; ++r)
            vq[r] = *(const float4*)((const char*)v2e + voff[r] + (unsigned)d * 4u);

        #pragma unroll
        for (int dd = 0; dd < 4; ++dd) {
            const float2 wq = *(const float2*)((const char*)W + (((unsigned)(d + dd)) << 11) + tb8);
            #pragma unroll
            for (int r = 0; r < R_BLK; ++r) {
                const float vs = (dd == 0) ? vq[r].x : (dd == 1) ? vq[r].y
                               : (dd == 2) ? vq[r].z : vq[r].w;
                acc2[r].x += wq.x * vs;
                acc2[r].y += wq.y * vs;
            }
        }
    }

    #pragma unroll
    for (int r = 0; r < R_BLK; ++r) {
        const float2 c2 = *(const float2*)(&cat_lds[r][2 * t]);
        float p = c2.x * acc2[r].x + c2.y * acc2[r].y;
        #pragma unroll
        for (int off = 32; off > 0; off >>= 1) p += __shfl_xor(p, off, 64);
        if (lane == 0) red_lds[r * 4 + wave] = p;
    }
    __syncthreads();

    if (t < R_BLK) {
        const int row = row0 + t;
        const int cnt = neighbor_counts[row];
        float s;
        if (cnt > 0) {
            s = red_lds[t * 4 + 0] + red_lds[t * 4 + 1]
              + red_lds[t * 4 + 2] + red_lds[t * 4 + 3] + bdot_lds[t];
        } else {
            s = selfdot_lds[t];
        }
        out[row] = s;
    }
}

// ============ fp32 fallback (ws too small): round-0 proven kernel ============
__global__ __launch_bounds__(THREADS, 4)
void easyrec_fused_f(const int* __restrict__ nodes_u,
                     const int* __restrict__ nodes_v,
                     const int* __restrict__ neighbors,
                     const int* __restrict__ neighbor_counts,
                     const float* __restrict__ u2e,
                     const float* __restrict__ v2e,
                     const float* __restrict__ W,
                     const float* __restrict__ bias,
                     float* __restrict__ out)
{
    __shared__ __align__(16) int   nbr_lds[R_BLK * K_NB];
    __shared__ __align__(16) float cat_lds[R_BLK][TWO_D];
    __shared__ float red_lds[R_BLK * 4];
    __shared__ float selfdot_lds[R_BLK];
    __shared__ float bdot_lds[R_BLK];

    const int t    = threadIdx.x;
    const int wave = t >> 6;
    const int lane = t & 63;
    const int row0 = blockIdx.x * R_BLK;

    nbr_lds[t]           = neighbors[(size_t)row0 * K_NB + t];
    nbr_lds[t + THREADS] = neighbors[(size_t)row0 * K_NB + t + THREADS];
    __syncthreads();

    for (int rr = 0; rr < 2; ++rr) {
        const int r   = wave + rr * 4;
        const int row = row0 + r;
        const int nu  = __builtin_amdgcn_readfirstlane(nodes_u[row]);
        const int nv  = __builtin_amdgcn_readfirstlane(nodes_v[row]);
        const int cnt = __builtin_amdgcn_readfirstlane(neighbor_counts[row]);

        const float4 self4 = *(const float4*)(u2e + (size_t)nu * D_DIM + 4 * lane);
        const float4 v4    = *(const float4*)(v2e + (size_t)nv * D_DIM + 4 * lane);
        const float4 b4    = *(const float4*)(bias + 4 * lane);

        float4 acc = make_float4(0.f, 0.f, 0.f, 0.f);
        const int base = r * K_NB;
        const int kmax = (cnt + 7) & ~7;
        for (int k = 0; k < kmax; k += 8) {
            const int4 ia = *(const int4*)&nbr_lds[base + k];
            const int4 ib = *(const int4*)&nbr_lds[base + k + 4];
            const float4 n0 = *(const float4*)(u2e + (size_t)ia.x * D_DIM + 4 * lane);
            const float4 n1 = *(const float4*)(u2e + (size_t)ia.y * D_DIM + 4 * lane);
            const float4 n2 = *(const float4*)(u2e + (size_t)ia.z * D_DIM + 4 * lane);
            const float4 n3 = *(const float4*)(u2e + (size_t)ia.w * D_DIM + 4 * lane);
            const float4 n4 = *(const float4*)(u2e + (size_t)ib.x * D_DIM + 4 * lane);
            const float4 n5 = *(const float4*)(u2e + (size_t)ib.y * D_DIM + 4 * lane);
            const float4 n6 = *(const float4*)(u2e + (size_t)ib.z * D_DIM + 4 * lane);
            const float4 n7 = *(const float4*)(u2e + (size_t)ib.w * D_DIM + 4 * lane);
            const float m0 = (k + 0 < cnt) ? 1.f : 0.f;
            const float m1 = (k + 1 < cnt) ? 1.f : 0.f;
            const float m2 = (k + 2 < cnt) ? 1.f : 0.f;
            const float m3 = (k + 3 < cnt) ? 1.f : 0.f;
            const float m4 = (k + 4 < cnt) ? 1.f : 0.f;
            const float m5 = (k + 5 < cnt) ? 1.f : 0.f;
            const float m6 = (k + 6 < cnt) ? 1.f : 0.f;
            const float m7 = (k + 7 < cnt) ? 1.f : 0.f;
            acc.x += n0.x*m0 + n1.x*m1 + n2.x*m2 + n3.x*m3 + n4.x*m4 + n5.x*m5 + n6.x*m6 + n7.x*m7;
            acc.y += n0.y*m0 + n1.y*m1 + n2.y*m2 + n3.y*m3 + n4.y*m4 + n5.y*m5 + n6.y*m6 + n7.y*m7;
            acc.z += n0.z*m0 + n1.z*m1 + n2.z*m2 + n3.z*m3 + n4.z*m4 + n5.z*m5 + n6.z*m6 + n7.z*m7;
            acc.w += n0.w*m0 + n1.w*m1 + n2.w*m2 + n3.w*m3 + n4.w*m4 + n5.w*m5 + n6.w*m6 + n7.w*m7;
        }
        const float inv = 1.0f / (float)(cnt > 0 ? cnt : 1);
        *(float4*)(&cat_lds[r][4 * lane])         = self4;
        *(float4*)(&cat_lds[r][D_DIM + 4 * lane]) =
            make_float4(acc.x * inv, acc.y * inv, acc.z * inv, acc.w * inv);

        float sv = self4.x * v4.x + self4.y * v4.y + self4.z * v4.z + self4.w * v4.w;
        float bv = b4.x * v4.x + b4.y * v4.y + b4.z * v4.z + b4.w * v4.w;
        #pragma unroll
        for (int off = 32; off > 0; off >>= 1) {
            sv += __shfl_xor(sv, off, 64);
            bv += __shfl_xor(bv, off, 64);
        }
        if (lane == 0) { selfdot_lds[r] = sv; bdot_lds[r] = bv; }
    }
    __syncthreads();

    const float* vrow[R_BLK];
    #pragma unroll
    for (int r = 0; r < R_BLK; ++r) {
        const int nv = __builtin_amdgcn_readfirstlane(nodes_v[row0 + r]);
        vrow[r] = v2e + (size_t)nv * D_DIM;
    }

    float2 acc2[R_BLK];
    #pragma unroll
    for (int r = 0; r < R_BLK; ++r) acc2[r] = make_float2(0.f, 0.f);

    for (int d = 0; d < D_DIM; d += 4) {
        float4 vq[R_BLK];
        #pragma unroll
        for (int r = 0; r < R_BLK; ++r) vq[r] = *(const float4*)(vrow[r] + d);
        #pragma unroll
        for (int dd = 0; dd < 4; ++dd) {
            const float2 wq = *(const float2*)(W + (size_t)(d + dd) * TWO_D + 2 * t);
            #pragma unroll
            for (int r = 0; r < R_BLK; ++r) {
                const float vs = (dd == 0) ? vq[r].x : (dd == 1) ? vq[r].y
                               : (dd == 2) ? vq[r].z : vq[r].w;
                acc2[r].x += wq.x * vs;
                acc2[r].y += wq.y * vs;
            }
        }
    }

    #pragma unroll
    for (int r = 0; r < R_BLK; ++r) {
        const float2 c2 = *(const float2*)(&cat_lds[r][2 * t]);
        float p = c2.x * acc2[r].x + c2.y * acc2[r].y;
        #pragma unroll
        for (int off = 32; off > 0; off >>= 1) p += __shfl_xor(p, off, 64);
        if (lane == 0) red_lds[r * 4 + wave] = p;
    }
    __syncthreads();

    if (t < R_BLK) {
        const int row = row0 + t;
        const int cnt = neighbor_counts[row];
        float s;
        if (cnt > 0) {
            s = red_lds[t * 4 + 0] + red_lds[t * 4 + 1]
              + red_lds[t * 4 + 2] + red_lds[t * 4 + 3] + bdot_lds[t];
        } else {
            s = selfdot_lds[t];
        }
        out[row] = s;
    }
}

extern "C" void kernel_launch(void* const* d_in, const int* in_sizes, int n_in,
                              void* d_out, int out_size, void* d_ws, size_t ws_size,
                              hipStream_t stream) {
    const int*   nodes_u         = (const int*)d_in[0];
    const int*   nodes_v         = (const int*)d_in[1];
    const int*   neighbors       = (const int*)d_in[2];
    const int*   neighbor_counts = (const int*)d_in[3];
    const float* u2e             = (const float*)d_in[4];
    const float* v2e             = (const float*)d_in[5];
    const float* W               = (const float*)d_in[6];
    const float* bias            = (const float*)d_in[7];
    float*       out             = (float*)d_out;

    const size_t need = (size_t)U_ROWS * D_DIM;   // 25.6 MB fp8 table
    const int blocks = B_ROWS / R_BLK;            // 2048

    if (d_ws != nullptr && ws_size >= need) {
        unsigned char* u8 = (unsigned char*)d_ws;
        const int n8 = U_ROWS * D_DIM / 8;        // 3.2M threads, 8 elems each
        const int cblocks = (n8 + 255) / 256;
        cvt_u2e_fp8<<<cblocks, 256, 0, stream>>>(u2e, (uint2*)u8, n8);
        easyrec_fused_q<<<blocks, THREADS, 0, stream>>>(
            nodes_u, nodes_v, neighbors, neighbor_counts, u2e, u8, v2e, W, bias, out);
    } else {
        easyrec_fused_f<<<blocks, THREADS, 0, stream>>>(
            nodes_u, nodes_v, neighbors, neighbor_counts, u2e, v2e, W, bias, out);
    }
}

// Round 6
// 292.282 us; speedup vs baseline: 1.1214x; 1.0353x over previous
//
#include <hip/hip_runtime.h>
#include <hip/hip_fp16.h>

#define B_ROWS   16384
#define K_NB     64
#define U_ROWS   100000
#define D_DIM    256
#define TWO_D    512
#define R_BLK    8          // rows per block
#define THREADS  256

typedef float f32x2_t __attribute__((ext_vector_type(2)));

#if __has_builtin(__builtin_amdgcn_cvt_pk_f32_fp8) && __has_builtin(__builtin_amdgcn_cvt_pk_fp8_f32)
#define FP8_HW 1
#else
#define FP8_HW 0
#include <hip/hip_fp8.h>
#endif

__device__ __forceinline__ unsigned pack4_fp8(float a, float b, float c, float d) {
#if FP8_HW
    int v = 0;
    v = __builtin_amdgcn_cvt_pk_fp8_f32(a, b, v, false);   // bytes 0-1
    v = __builtin_amdgcn_cvt_pk_fp8_f32(c, d, v, true);    // bytes 2-3
    return (unsigned)v;
#else
    __hip_fp8_e4m3 x0(a), x1(b), x2(c), x3(d);
    return (unsigned)x0.__x | ((unsigned)x1.__x << 8)
         | ((unsigned)x2.__x << 16) | ((unsigned)x3.__x << 24);
#endif
}

__device__ __forceinline__ float4 unpack4_fp8(unsigned u) {
#if FP8_HW
    const f32x2_t lo = __builtin_amdgcn_cvt_pk_f32_fp8((int)u, false);
    const f32x2_t hi = __builtin_amdgcn_cvt_pk_f32_fp8((int)u, true);
    return make_float4(lo[0], lo[1], hi[0], hi[1]);
#else
    __hip_fp8_e4m3 x0, x1, x2, x3;
    x0.__x = u & 0xff; x1.__x = (u >> 8) & 0xff;
    x2.__x = (u >> 16) & 0xff; x3.__x = (u >> 24) & 0xff;
    return make_float4((float)x0, (float)x1, (float)x2, (float)x3);
#endif
}

// ============ pre-pass: u2e fp32 -> fp8 e4m3 (row-major [U][256]) ============
__global__ __launch_bounds__(256)
void cvt_u2e_fp8(const float* __restrict__ src, uint2* __restrict__ dst, int n8) {
    const int i = blockIdx.x * 256 + threadIdx.x;
    if (i >= n8) return;
    const float4 a = ((const float4*)src)[2 * i];
    const float4 b = ((const float4*)src)[2 * i + 1];
    uint2 o;
    o.x = pack4_fp8(a.x, a.y, a.z, a.w);
    o.y = pack4_fp8(b.x, b.y, b.z, b.w);
    dst[i] = o;
}

// ============ main fused kernel: wave-specialized overlap ============
// Evidence r0-r5: phase-1 = 66us FIXED + bytes-term (now 17us); phase-2 (~30us,
// W-stream, L2-resident) runs serially after it but uses a different memory
// path. This version overlaps them: waves 0-1 gather (proven R5 dual-row fp8
// structure, 2 pairs each), waves 2-3 compute t = W^T v concurrently (it has
// no dependence on the gather). One sync, then matvec waves do the cat.t dot.
__global__ __launch_bounds__(THREADS, 4)
void easyrec_fused_q(const int* __restrict__ nodes_u,
                     const int* __restrict__ nodes_v,
                     const int* __restrict__ neighbors,
                     const int* __restrict__ neighbor_counts,
                     const float* __restrict__ u2e,
                     const unsigned char* __restrict__ u8,  // fp8 copy of u2e
                     const float* __restrict__ v2e,
                     const float* __restrict__ W,     // [D, 2D] row-major
                     const float* __restrict__ bias,  // [D]
                     float* __restrict__ out)         // [B]
{
    __shared__ __align__(16) int   nbr_lds[R_BLK * K_NB];
    __shared__ __align__(16) float cat_lds[R_BLK][TWO_D];
    __shared__ float red_lds[R_BLK * 2];
    __shared__ float selfdot_lds[R_BLK];
    __shared__ float bdot_lds[R_BLK];

    const int t    = threadIdx.x;
    const int wave = t >> 6;
    const int lane = t & 63;
    const int row0 = blockIdx.x * R_BLK;

    // stage neighbor indices (all 256 threads, coalesced)
    nbr_lds[t]           = neighbors[(size_t)row0 * K_NB + t];
    nbr_lds[t + THREADS] = neighbors[(size_t)row0 * K_NB + t + THREADS];
    __syncthreads();

    if (wave < 2) {
        // ================= GATHER role (waves 0-1) =================
        const unsigned colb = (unsigned)lane * 16u;
        const unsigned colq = (unsigned)lane * 4u;

        // preamble: self/v/bias dots + self->cat for this wave's 4 rows
        {
            const float4 b4 = *(const float4*)((const char*)bias + colb);
            #pragma unroll
            for (int rr = 0; rr < 4; ++rr) {
                const int r   = wave * 2 + (rr & 1) + (rr >> 1) * 4;
                const int row = row0 + r;
                const int nu  = __builtin_amdgcn_readfirstlane(nodes_u[row]);
                const int nv  = __builtin_amdgcn_readfirstlane(nodes_v[row]);
                const float4 self4 = *(const float4*)((const char*)u2e + (((size_t)nu) << 10) + colb);
                const float4 v4    = *(const float4*)((const char*)v2e + (((size_t)nv) << 10) + colb);
                *(float4*)(&cat_lds[r][4 * lane]) = self4;
                float sv = self4.x * v4.x + self4.y * v4.y + self4.z * v4.z + self4.w * v4.w;
                float bv = b4.x * v4.x + b4.y * v4.y + b4.z * v4.z + b4.w * v4.w;
                #pragma unroll
                for (int off = 32; off > 0; off >>= 1) {
                    sv += __shfl_xor(sv, off, 64);
                    bv += __shfl_xor(bv, off, 64);
                }
                if (lane == 0) { selfdot_lds[r] = sv; bdot_lds[r] = bv; }
            }
        }

#define LOADQ8(P, BASE, KK)                                                         \
    const int4 P##ia = *(const int4*)&nbr_lds[(BASE) + (KK)];                       \
    const int4 P##ib = *(const int4*)&nbr_lds[(BASE) + (KK) + 4];                   \
    const unsigned P##n0 = *(const unsigned*)(u8 + (((unsigned)P##ia.x) << 8) + colq); \
    const unsigned P##n1 = *(const unsigned*)(u8 + (((unsigned)P##ia.y) << 8) + colq); \
    const unsigned P##n2 = *(const unsigned*)(u8 + (((unsigned)P##ia.z) << 8) + colq); \
    const unsigned P##n3 = *(const unsigned*)(u8 + (((unsigned)P##ia.w) << 8) + colq); \
    const unsigned P##n4 = *(const unsigned*)(u8 + (((unsigned)P##ib.x) << 8) + colq); \
    const unsigned P##n5 = *(const unsigned*)(u8 + (((unsigned)P##ib.y) << 8) + colq); \
    const unsigned P##n6 = *(const unsigned*)(u8 + (((unsigned)P##ib.z) << 8) + colq); \
    const unsigned P##n7 = *(const unsigned*)(u8 + (((unsigned)P##ib.w) << 8) + colq);

#define ACCQ1(P, N, ACC, M)                                                         \
    {                                                                               \
        const float4 f = unpack4_fp8(P##N);                                         \
        ACC.x += (M) * f.x; ACC.y += (M) * f.y;                                     \
        ACC.z += (M) * f.z; ACC.w += (M) * f.w;                                     \
    }

#define ACCQ8(P, ACC, CNT, KK)                                                      \
    {                                                                               \
        const float m0 = ((KK) + 0 < (CNT)) ? 1.f : 0.f;                            \
        const float m1 = ((KK) + 1 < (CNT)) ? 1.f : 0.f;                            \
        const float m2 = ((KK) + 2 < (CNT)) ? 1.f : 0.f;                            \
        const float m3 = ((KK) + 3 < (CNT)) ? 1.f : 0.f;                            \
        const float m4 = ((KK) + 4 < (CNT)) ? 1.f : 0.f;                            \
        const float m5 = ((KK) + 5 < (CNT)) ? 1.f : 0.f;                            \
        const float m6 = ((KK) + 6 < (CNT)) ? 1.f : 0.f;                            \
        const float m7 = ((KK) + 7 < (CNT)) ? 1.f : 0.f;                            \
        ACCQ1(P, n0, ACC, m0) ACCQ1(P, n1, ACC, m1)                                 \
        ACCQ1(P, n2, ACC, m2) ACCQ1(P, n3, ACC, m3)                                 \
        ACCQ1(P, n4, ACC, m4) ACCQ1(P, n5, ACC, m5)                                 \
        ACCQ1(P, n6, ACC, m6) ACCQ1(P, n7, ACC, m7)                                 \
    }

        // two dual-row pairs: wave0 -> (0,4),(1,5); wave1 -> (2,6),(3,7)
        for (int pp = 0; pp < 2; ++pp) {
            const int rA = wave * 2 + pp;
            const int rB = rA + 4;
            const int cntA = __builtin_amdgcn_readfirstlane(neighbor_counts[row0 + rA]);
            const int cntB = __builtin_amdgcn_readfirstlane(neighbor_counts[row0 + rB]);
            const int itA = (cntA + 7) >> 3;
            const int itB = (cntB + 7) >> 3;
            const int itMin = itA < itB ? itA : itB;
            const int itMax = itA > itB ? itA : itB;
            const int baseA = rA * K_NB;
            const int baseB = rB * K_NB;

            float4 accA = make_float4(0.f, 0.f, 0.f, 0.f);
            float4 accB = make_float4(0.f, 0.f, 0.f, 0.f);

            for (int i = 0; i < itMin; ++i) {
                const int k = i << 3;
                LOADQ8(A, baseA, k)
                LOADQ8(B, baseB, k)
                ACCQ8(A, accA, cntA, k)
                ACCQ8(B, accB, cntB, k)
            }
            if (itMin < itMax) {
                const bool Along = itA > itB;
                const int  cntL  = Along ? cntA : cntB;
                const int  baseL = Along ? baseA : baseB;
                float4 accL = make_float4(0.f, 0.f, 0.f, 0.f);
                for (int i = itMin; i < itMax; ++i) {
                    const int k = i << 3;
                    LOADQ8(L, baseL, k)
                    ACCQ8(L, accL, cntL, k)
                }
                if (Along) {
                    accA.x += accL.x; accA.y += accL.y; accA.z += accL.z; accA.w += accL.w;
                } else {
                    accB.x += accL.x; accB.y += accL.y; accB.z += accL.z; accB.w += accL.w;
                }
            }

            const float invA = 1.0f / (float)(cntA > 0 ? cntA : 1);
            const float invB = 1.0f / (float)(cntB > 0 ? cntB : 1);
            *(float4*)(&cat_lds[rA][D_DIM + 4 * lane]) =
                make_float4(accA.x * invA, accA.y * invA, accA.z * invA, accA.w * invA);
            *(float4*)(&cat_lds[rB][D_DIM + 4 * lane]) =
                make_float4(accB.x * invB, accB.y * invB, accB.z * invB, accB.w * invB);
        }
#undef LOADQ8
#undef ACCQ8
#undef ACCQ1
    } else {
        // ================= MATVEC role (waves 2-3) =================
        // t_j = sum_d W[d, j] * v[d]; thread tm owns j = 4*tm .. 4*tm+3.
        const int tm = t - 128;      // 0..127
        unsigned voff[R_BLK];
        #pragma unroll
        for (int r = 0; r < R_BLK; ++r) {
            const int nv = __builtin_amdgcn_readfirstlane(nodes_v[row0 + r]);
            voff[r] = ((unsigned)nv) << 10;
        }

        float4 acc4[R_BLK];
        #pragma unroll
        for (int r = 0; r < R_BLK; ++r) acc4[r] = make_float4(0.f, 0.f, 0.f, 0.f);

        const unsigned tb16 = (unsigned)tm * 16u;
        for (int d = 0; d < D_DIM; d += 4) {
            float4 vq[R_BLK];
            #pragma unroll
            for (int r = 0; r < R_BLK; ++r)
                vq[r] = *(const float4*)((const char*)v2e + voff[r] + (unsigned)d * 4u);

            #pragma unroll
            for (int dd = 0; dd < 4; ++dd) {
                const float4 w4 = *(const float4*)((const char*)W + (((unsigned)(d + dd)) << 11) + tb16);
                #pragma unroll
                for (int r = 0; r < R_BLK; ++r) {
                    const float vs = (dd == 0) ? vq[r].x : (dd == 1) ? vq[r].y
                                   : (dd == 2) ? vq[r].z : vq[r].w;
                    acc4[r].x += w4.x * vs;
                    acc4[r].y += w4.y * vs;
                    acc4[r].z += w4.z * vs;
                    acc4[r].w += w4.w * vs;
                }
            }
        }
        __syncthreads();   // wait for cat_lds (gather waves)

        // epilogue: score_r = sum_j cat[r][j] * t_j, reduced across 2 waves
        #pragma unroll
        for (int r = 0; r < R_BLK; ++r) {
            const float4 c4 = *(const float4*)(&cat_lds[r][4 * tm]);
            float p = c4.x * acc4[r].x + c4.y * acc4[r].y
                    + c4.z * acc4[r].z + c4.w * acc4[r].w;
            #pragma unroll
            for (int off = 32; off > 0; off >>= 1) p += __shfl_xor(p, off, 64);
            if (lane == 0) red_lds[r * 2 + (wave - 2)] = p;
        }
    }

    if (wave < 2) __syncthreads();   // gather waves' matching barrier
    __syncthreads();

    if (t < R_BLK) {
        const int row = row0 + t;
        const int cnt = neighbor_counts[row];
        float s;
        if (cnt > 0) {
            s = red_lds[t * 2 + 0] + red_lds[t * 2 + 1] + bdot_lds[t];
        } else {
            s = selfdot_lds[t];
        }
        out[row] = s;
    }
}

// ============ fp32 fallback (ws too small): round-0 proven kernel ============
__global__ __launch_bounds__(THREADS, 4)
void easyrec_fused_f(const int* __restrict__ nodes_u,
                     const int* __restrict__ nodes_v,
                     const int* __restrict__ neighbors,
                     const int* __restrict__ neighbor_counts,
                     const float* __restrict__ u2e,
                     const float* __restrict__ v2e,
                     const float* __restrict__ W,
                     const float* __restrict__ bias,
                     float* __restrict__ out)
{
    __shared__ __align__(16) int   nbr_lds[R_BLK * K_NB];
    __shared__ __align__(16) float cat_lds[R_BLK][TWO_D];
    __shared__ float red_lds[R_BLK * 4];
    __shared__ float selfdot_lds[R_BLK];
    __shared__ float bdot_lds[R_BLK];

    const int t    = threadIdx.x;
    const int wave = t >> 6;
    const int lane = t & 63;
    const int row0 = blockIdx.x * R_BLK;

    nbr_lds[t]           = neighbors[(size_t)row0 * K_NB + t];
    nbr_lds[t + THREADS] = neighbors[(size_t)row0 * K_NB + t + THREADS];
    __syncthreads();

    for (int rr = 0; rr < 2; ++rr) {
        const int r   = wave + rr * 4;
        const int row = row0 + r;
        const int nu  = __builtin_amdgcn_readfirstlane(nodes_u[row]);
        const int nv  = __builtin_amdgcn_readfirstlane(nodes_v[row]);
        const int cnt = __builtin_amdgcn_readfirstlane(neighbor_counts[row]);

        const float4 self4 = *(const float4*)(u2e + (size_t)nu * D_DIM + 4 * lane);
        const float4 v4    = *(const float4*)(v2e + (size_t)nv * D_DIM + 4 * lane);
        const float4 b4    = *(const float4*)(bias + 4 * lane);

        float4 acc = make_float4(0.f, 0.f, 0.f, 0.f);
        const int base = r * K_NB;
        const int kmax = (cnt + 7) & ~7;
        for (int k = 0; k < kmax; k += 8) {
            const int4 ia = *(const int4*)&nbr_lds[base + k];
            const int4 ib = *(const int4*)&nbr_lds[base + k + 4];
            const float4 n0 = *(const float4*)(u2e + (size_t)ia.x * D_DIM + 4 * lane);
            const float4 n1 = *(const float4*)(u2e + (size_t)ia.y * D_DIM + 4 * lane);
            const float4 n2 = *(const float4*)(u2e + (size_t)ia.z * D_DIM + 4 * lane);
            const float4 n3 = *(const float4*)(u2e + (size_t)ia.w * D_DIM + 4 * lane);
            const float4 n4 = *(const float4*)(u2e + (size_t)ib.x * D_DIM + 4 * lane);
            const float4 n5 = *(const float4*)(u2e + (size_t)ib.y * D_DIM + 4 * lane);
            const float4 n6 = *(const float4*)(u2e + (size_t)ib.z * D_DIM + 4 * lane);
            const float4 n7 = *(const float4*)(u2e + (size_t)ib.w * D_DIM + 4 * lane);
            const float m0 = (k + 0 < cnt) ? 1.f : 0.f;
            const float m1 = (k + 1 < cnt) ? 1.f : 0.f;
            const float m2 = (k + 2 < cnt) ? 1.f : 0.f;
            const float m3 = (k + 3 < cnt) ? 1.f : 0.f;
            const float m4 = (k + 4 < cnt) ? 1.f : 0.f;
            const float m5 = (k + 5 < cnt) ? 1.f : 0.f;
            const float m6 = (k + 6 < cnt) ? 1.f : 0.f;
            const float m7 = (k + 7 < cnt) ? 1.f : 0.f;
            acc.x += n0.x*m0 + n1.x*m1 + n2.x*m2 + n3.x*m3 + n4.x*m4 + n5.x*m5 + n6.x*m6 + n7.x*m7;
            acc.y += n0.y*m0 + n1.y*m1 + n2.y*m2 + n3.y*m3 + n4.y*m4 + n5.y*m5 + n6.y*m6 + n7.y*m7;
            acc.z += n0.z*m0 + n1.z*m1 + n2.z*m2 + n3.z*m3 + n4.z*m4 + n5.z*m5 + n6.z*m6 + n7.z*m7;
            acc.w += n0.w*m0 + n1.w*m1 + n2.w*m2 + n3.w*m3 + n4.w*m4 + n5.w*m5 + n6.w*m6 + n7.w*m7;
        }
        const float inv = 1.0f / (float)(cnt > 0 ? cnt : 1);
        *(float4*)(&cat_lds[r][4 * lane])         = self4;
        *(float4*)(&cat_lds[r][D_DIM + 4 * lane]) =
            make_float4(acc.x * inv, acc.y * inv, acc.z * inv, acc.w * inv);

        float sv = self4.x * v4.x + self4.y * v4.y + self4.z * v4.z + self4.w * v4.w;
        float bv = b4.x * v4.x + b4.y * v4.y + b4.z * v4.z + b4.w * v4.w;
        #pragma unroll
        for (int off = 32; off > 0; off >>= 1) {
            sv += __shfl_xor(sv, off, 64);
            bv += __shfl_xor(bv, off, 64);
        }
        if (lane == 0) { selfdot_lds[r] = sv; bdot_lds[r] = bv; }
    }
    __syncthreads();

    const float* vrow[R_BLK];
    #pragma unroll
    for (int r = 0; r < R_BLK; ++r) {
        const int nv = __builtin_amdgcn_readfirstlane(nodes_v[row0 + r]);
        vrow[r] = v2e + (size_t)nv * D_DIM;
    }

    float2 acc2[R_BLK];
    #pragma unroll
    for (int r = 0; r < R_BLK; ++r) acc2[r] = make_float2(0.f, 0.f);

    for (int d = 0; d < D_DIM; d += 4) {
        float4 vq[R_BLK];
        #pragma unroll
        for (int r = 0; r < R_BLK; ++r) vq[r] = *(const float4*)(vrow[r] + d);
        #pragma unroll
        for (int dd = 0; dd < 4; ++dd) {
            const float2 wq = *(const float2*)(W + (size_t)(d + dd) * TWO_D + 2 * t);
            #pragma unroll
            for (int r = 0; r < R_BLK; ++r) {
                const float vs = (dd == 0) ? vq[r].x : (dd == 1) ? vq[r].y
                               : (dd == 2) ? vq[r].z : vq[r].w;
                acc2[r].x += wq.x * vs;
                acc2[r].y += wq.y * vs;
            }
        }
    }

    #pragma unroll
    for (int r = 0; r < R_BLK; ++r) {
        const float2 c2 = *(const float2*)(&cat_lds[r][2 * t]);
        float p = c2.x * acc2[r].x + c2.y * acc2[r].y;
        #pragma unroll
        for (int off = 32; off > 0; off >>= 1) p += __shfl_xor(p, off, 64);
        if (lane == 0) red_lds[r * 4 + wave] = p;
    }
    __syncthreads();

    if (t < R_BLK) {
        const int row = row0 + t;
        const int cnt = neighbor_counts[row];
        float s;
        if (cnt > 0) {
            s = red_lds[t * 4 + 0] + red_lds[t * 4 + 1]
              + red_lds[t * 4 + 2] + red_lds[t * 4 + 3] + bdot_lds[t];
        } else {
            s = selfdot_lds[t];
        }
        out[row] = s;
    }
}

extern "C" void kernel_launch(void* const* d_in, const int* in_sizes, int n_in,
                              void* d_out, int out_size, void* d_ws, size_t ws_size,
                              hipStream_t stream) {
    const int*   nodes_u         = (const int*)d_in[0];
    const int*   nodes_v         = (const int*)d_in[1];
    const int*   neighbors       = (const int*)d_in[2];
    const int*   neighbor_counts = (const int*)d_in[3];
    const float* u2e             = (const float*)d_in[4];
    const float* v2e             = (const float*)d_in[5];
    const float* W               = (const float*)d_in[6];
    const float* bias            = (const float*)d_in[7];
    float*       out             = (float*)d_out;

    const size_t need = (size_t)U_ROWS * D_DIM;   // 25.6 MB fp8 table
    const int blocks = B_ROWS / R_BLK;            // 2048

    if (d_ws != nullptr && ws_size >= need) {
        unsigned char* u8 = (unsigned char*)d_ws;
        const int n8 = U_ROWS * D_DIM / 8;        // 3.2M threads, 8 elems each
        const int cblocks = (n8 + 255) / 256;
        cvt_u2e_fp8<<<cblocks, 256, 0, stream>>>(u2e, (uint2*)u8, n8);
        easyrec_fused_q<<<blocks, THREADS, 0, stream>>>(
            nodes_u, nodes_v, neighbors, neighbor_counts, u2e, u8, v2e, W, bias, out);
    } else {
        easyrec_fused_f<<<blocks, THREADS, 0, stream>>>(
            nodes_u, nodes_v, neighbors, neighbor_counts, u2e, v2e, W, bias, out);
    }
}